// Round 6
// baseline (166.380 us; speedup 1.0000x reference)
//
#include <hip/hip_runtime.h>
#include <math.h>

#define ROW_C 512
#define NBIN 2048          // bins = bits [22:12] of float(clamp(x,+-7.9)+24.0)
#define NPACK (NBIN / 2)   // two u16 counters per int -> 1024 ints = 4KB/wave

// One wave per row, 8 elements/lane. K in {256,341,384,409}:
//  1. value-uniform 2048-bin histogram (packed u16x2, per-wave LDS, swizzled).
//  2. packed in-register prefix + one cross-lane scan; prefix written to LDS.
//  3. bin locate per rank: ballot on register lane-totals finds owner lane,
//     16 lanes read owner's prefix words in parallel, 2 ballots find the bin.
//     (replaces R5's 11 serially-dependent LDS reads)
//  4. exact tail: all four ranks' peel-max rounds interleaved in one loop
//     (4 independent shfl chains overlap; scalar tcut instead of candidate
//     array). Tie-break lowest-original-index matches jax.lax.top_k.
// No __syncthreads anywhere (wave-private LDS, in-order DS pipe).
__global__ __launch_bounds__(256) void topk_ms_kernel(
    const float* __restrict__ attn,
    const float* __restrict__ w1p, const float* __restrict__ w2p,
    const float* __restrict__ w3p, const float* __restrict__ w4p,
    float* __restrict__ out)
{
    __shared__ __align__(16) unsigned hist_all[4][NPACK];

    const int lane = threadIdx.x & 63;
    const int wv   = threadIdx.x >> 6;
    unsigned* h = hist_all[wv];
    int4* hv = (int4*)h;

    const long long row  = (long long)blockIdx.x * 4 + wv;
    const long long base = row * ROW_C + lane * 8;

    const float4 A = *reinterpret_cast<const float4*>(attn + base);
    const float4 B = *reinterpret_cast<const float4*>(attn + base + 4);
    float orig[8] = {A.x, A.y, A.z, A.w, B.x, B.y, B.z, B.w};

    unsigned key[8];
    int bin[8];
    #pragma unroll
    for (int s = 0; s < 8; ++s) {
        const unsigned u = __float_as_uint(orig[s]);
        key[s] = (u & 0x80000000u) ? ~u : (u | 0x80000000u);  // order-isomorphic
        const float y = fminf(fmaxf(orig[s], -7.9f), 7.9f) + 24.0f;  // fixed exp
        bin[s] = (int)((__float_as_uint(y) >> 12) & 0x7FFu);         // monotone
    }

    // ---- zero histogram ----
    {
        const int4 z = make_int4(0, 0, 0, 0);
        hv[lane] = z; hv[lane + 64] = z; hv[lane + 128] = z; hv[lane + 192] = z;
    }

    // ---- histogram: packed atomics, swizzled word addressing ----
    #pragma unroll
    for (int s = 0; s < 8; ++s) {
        const int j  = bin[s] >> 1;
        const int ph = j ^ (((j >> 5) & 7) << 2);
        atomicAdd(&h[ph], (bin[s] & 1) ? 0x10000u : 1u);
    }

    // ---- read own 32 bins, packed in-register prefix ----
    unsigned pp[16];
    #pragma unroll
    for (int k = 0; k < 4; ++k) {
        const int b  = 4 * lane + k;
        const int pb = b ^ ((b >> 3) & 7);
        const int4 v = hv[pb];
        pp[4 * k]     = (unsigned)v.x;
        pp[4 * k + 1] = (unsigned)v.y;
        pp[4 * k + 2] = (unsigned)v.z;
        pp[4 * k + 3] = (unsigned)v.w;
    }
    unsigned run = 0;
    #pragma unroll
    for (int j = 0; j < 16; ++j) {
        const unsigned q = pp[j] + (pp[j] << 16);  // (lo, lo+hi)
        pp[j] = q + run * 0x10001u;
        run = pp[j] >> 16;
    }
    unsigned incl = run;   // cross-lane inclusive scan of lane totals
    #pragma unroll
    for (int off = 1; off < 64; off <<= 1) {
        const unsigned t = __shfl_up(incl, off, 64);
        if (lane >= off) incl += t;
    }
    const unsigned bmul = (incl - run) * 0x10001u;
    #pragma unroll
    for (int j = 0; j < 16; ++j) pp[j] += bmul;
    #pragma unroll
    for (int k = 0; k < 4; ++k) {
        const int b  = 4 * lane + k;
        const int pb = b ^ ((b >> 3) & 7);
        hv[pb] = make_int4((int)pp[4 * k], (int)pp[4 * k + 1],
                           (int)pp[4 * k + 2], (int)pp[4 * k + 3]);
    }

    // ---- locate threshold bin per rank: ballot + one parallel LDS read ----
    const int KS[4] = {256, 341, 384, 409};
    int b_r[4], R_r[4];
    const int w15 = lane & 15;
    #pragma unroll
    for (int r = 0; r < 4; ++r) {
        const int T = 513 - KS[r];   // smallest bin with incl prefix >= T
        const unsigned long long ob = __ballot((int)incl >= T);
        const int owner = __ffsll(ob) - 1;          // first lane crossing T
        const int g  = (owner << 4) | w15;          // owner's word w15
        const int pg = g ^ (((g >> 5) & 7) << 2);
        const unsigned pv = h[pg];
        const int lo = (int)(pv & 0xFFFFu), hi = (int)(pv >> 16);
        const unsigned bl = (unsigned)__ballot(lo >= T) & 0xFFFFu;
        const unsigned bh = (unsigned)__ballot(hi >= T) & 0xFFFFu;  // nonzero
        const int binl_l = bl ? (2 * (__ffs(bl) - 1)) : 1000;
        const int binl_h = 2 * (__ffs(bh) - 1) + 1;
        const int binl = min(binl_l, binl_h);       // first crossing bin
        const unsigned pvs = __shfl(pv, binl >> 1, 64);
        const int pref = (binl & 1) ? (int)(pvs >> 16) : (int)(pvs & 0xFFFFu);
        b_r[r] = (owner << 5) + binl;
        R_r[r] = KS[r] - 512 + pref;                // within-bin rank (>=1)
    }

    // ---- exact tail: interleaved peel-max rounds over all four ranks ----
    unsigned tk[4];
    int need[4], cnteq[4];
    unsigned tcut[4] = {0xFFFFFFFFu, 0xFFFFFFFFu, 0xFFFFFFFFu, 0xFFFFFFFFu};
    int done = 0;
    while (done != 15) {
        unsigned lmax[4];
        #pragma unroll
        for (int r = 0; r < 4; ++r) {
            unsigned mk = 0;
            #pragma unroll
            for (int s = 0; s < 8; ++s) {
                const unsigned v =
                    (bin[s] == b_r[r] && key[s] < tcut[r]) ? key[s] : 0u;
                mk = (v > mk) ? v : mk;
            }
            lmax[r] = mk;
        }
        #pragma unroll
        for (int off = 32; off >= 1; off >>= 1) {
            #pragma unroll
            for (int r = 0; r < 4; ++r) {
                const unsigned o = __shfl_xor(lmax[r], off, 64);
                lmax[r] = (o > lmax[r]) ? o : lmax[r];
            }
        }
        int cnt[4];
        #pragma unroll
        for (int r = 0; r < 4; ++r) {
            int c = 0;
            #pragma unroll
            for (int s = 0; s < 8; ++s)
                c += (int)__popcll(__ballot(key[s] == lmax[r]));
            cnt[r] = c;  // equal keys => equal values => same bin, still active
        }
        #pragma unroll
        for (int r = 0; r < 4; ++r) {
            if (!(done & (1 << r))) {
                if (cnt[r] >= R_r[r]) {
                    tk[r] = lmax[r]; need[r] = R_r[r]; cnteq[r] = cnt[r];
                    done |= (1 << r);
                } else {
                    R_r[r] -= cnt[r];
                    tcut[r] = lmax[r];
                }
            }
        }
    }

    // ---- membership flags ----
    int fl[8] = {0, 0, 0, 0, 0, 0, 0, 0};
    const bool anytie = (need[0] != cnteq[0]) | (need[1] != cnteq[1]) |
                        (need[2] != cnteq[2]) | (need[3] != cnteq[3]);
    if (!anytie) {   // common: admitting all ==t gives exactly K
        #pragma unroll
        for (int s = 0; s < 8; ++s) {
            fl[s] = (int)(key[s] >= tk[0])
                  | ((int)(key[s] >= tk[1]) << 1)
                  | ((int)(key[s] >= tk[2]) << 2)
                  | ((int)(key[s] >= tk[3]) << 3);
        }
    } else {         // rare: admit lowest original indices among ties
        const unsigned long long ltm = (1ull << lane) - 1ull;
        #pragma unroll
        for (int r = 0; r < 4; ++r) {
            const unsigned t = tk[r];
            if (need[r] == cnteq[r]) {
                #pragma unroll
                for (int s = 0; s < 8; ++s)
                    fl[s] |= ((int)(key[s] >= t)) << r;
            } else {
                int basec = 0;
                #pragma unroll
                for (int s = 0; s < 8; ++s)
                    basec += (int)__popcll(__ballot(key[s] == t) & ltm);
                int own = 0;
                #pragma unroll
                for (int s = 0; s < 8; ++s) {
                    const bool eq = (key[s] == t);
                    if (key[s] > t || (eq && (basec + own) < need[r]))
                        fl[s] |= (1 << r);
                    own += eq ? 1 : 0;
                }
            }
        }
    }

    // ---- softmax denominators (shift-invariant: no max subtraction) ----
    float eo[8];
    #pragma unroll
    for (int s = 0; s < 8; ++s) eo[s] = __expf(orig[s]);

    float z0 = 0.f, z1 = 0.f, z2 = 0.f, z3 = 0.f;
    #pragma unroll
    for (int s = 0; s < 8; ++s) {
        z0 += (fl[s] & 1) ? eo[s] : 0.f;
        z1 += (fl[s] & 2) ? eo[s] : 0.f;
        z2 += (fl[s] & 4) ? eo[s] : 0.f;
        z3 += (fl[s] & 8) ? eo[s] : 0.f;
    }
    #pragma unroll
    for (int off = 32; off >= 1; off >>= 1) {
        z0 += __shfl_xor(z0, off, 64);
        z1 += __shfl_xor(z1, off, 64);
        z2 += __shfl_xor(z2, off, 64);
        z3 += __shfl_xor(z3, off, 64);
    }

    const float wz0 = w1p[0] * __builtin_amdgcn_rcpf(z0);
    const float wz1 = w2p[0] * __builtin_amdgcn_rcpf(z1);
    const float wz2 = w3p[0] * __builtin_amdgcn_rcpf(z2);
    const float wz3 = w4p[0] * __builtin_amdgcn_rcpf(z3);

    // ---- epilogue ----
    float res[8];
    #pragma unroll
    for (int s = 0; s < 8; ++s) {
        float c = 0.f;
        c += (fl[s] & 1) ? wz0 : 0.f;
        c += (fl[s] & 2) ? wz1 : 0.f;
        c += (fl[s] & 4) ? wz2 : 0.f;
        c += (fl[s] & 8) ? wz3 : 0.f;
        res[s] = eo[s] * c;
    }
    *reinterpret_cast<float4*>(out + base)     = make_float4(res[0], res[1], res[2], res[3]);
    *reinterpret_cast<float4*>(out + base + 4) = make_float4(res[4], res[5], res[6], res[7]);
}

extern "C" void kernel_launch(void* const* d_in, const int* in_sizes, int n_in,
                              void* d_out, int out_size, void* d_ws, size_t ws_size,
                              hipStream_t stream) {
    const float* attn = (const float*)d_in[0];
    const float* w1   = (const float*)d_in[1];
    const float* w2   = (const float*)d_in[2];
    const float* w3   = (const float*)d_in[3];
    const float* w4   = (const float*)d_in[4];
    float* out = (float*)d_out;

    int rows = in_sizes[0] / ROW_C;      // 8*8*512 = 32768
    int blocks = (rows + 3) / 4;         // 4 waves (rows) per 256-thread block
    topk_ms_kernel<<<blocks, 256, 0, stream>>>(attn, w1, w2, w3, w4, out);
}